// Round 4
// baseline (43.154 us; speedup 1.0000x reference)
//
#include <hip/hip_runtime.h>

// ---------------------------------------------------------------------------
// WeightedRandomSampler (inverse-CDF multinomial):
//   cdf = cumsum(freq); idx = searchsorted(cdf, u*cdf[-1], 'right'); clip; float
//
// 3-kernel plan:
//   1) scan_kernel : single-block chunked prefix sum freq[V] -> cdf[V] (ws)
//   2) lut_kernel  : bucket LUT over key-space; lut[b] = {searchR(total*b/L),
//                    cdf[idx]} packed in 8B. L = power of two -> exact b/L.
//   3) sample_kernel: per sample, b = floor(u*L) (exact), answer bounded by
//                    [lut[b].idx, lut[b+1].idx]; width 0/1 resolved from the
//                    packed cdf value (no cdf load); rare wide buckets binary-
//                    search global cdf. 4 samples/thread for ILP + float4 IO.
// ---------------------------------------------------------------------------

#define SCAN_T 1024

__global__ __launch_bounds__(SCAN_T) void scan_kernel(const float* __restrict__ freq,
                                                      float* __restrict__ cdf, int V) {
    __shared__ float sums[SCAN_T];
    const int t = threadIdx.x;
    int C = (V + SCAN_T - 1) / SCAN_T;
    C = (C + 3) & ~3;                      // chunk multiple of 4 -> float4-aligned
    const int begin = t * C;
    const int end = (begin + C < V) ? (begin + C) : V;

    // phase 1: per-thread chunk sum (vectorized)
    float s = 0.f;
    int i = begin;
    for (; i + 3 < end; i += 4) {
        const float4 v = *reinterpret_cast<const float4*>(freq + i);
        s += v.x + v.y + v.z + v.w;
    }
    for (; i < end; ++i) s += freq[i];
    sums[t] = s;
    __syncthreads();

    // phase 2: Hillis-Steele inclusive scan of 1024 partials
    for (int off = 1; off < SCAN_T; off <<= 1) {
        const float v = (t >= off) ? sums[t - off] : 0.f;
        __syncthreads();
        sums[t] += v;
        __syncthreads();
    }
    float run = sums[t] - s;               // exclusive base for this chunk

    // phase 3: re-walk chunk, write running prefix
    for (i = begin; i + 3 < end; i += 4) {
        const float4 v = *reinterpret_cast<const float4*>(freq + i);
        float4 o;
        run += v.x; o.x = run;
        run += v.y; o.y = run;
        run += v.z; o.z = run;
        run += v.w; o.w = run;
        *reinterpret_cast<float4*>(cdf + i) = o;
    }
    for (; i < end; ++i) { run += freq[i]; cdf[i] = run; }
}

__global__ __launch_bounds__(256) void lut_kernel(const float* __restrict__ cdf, int V,
                                                  int2* __restrict__ lut, int L) {
    const int b = blockIdx.x * blockDim.x + threadIdx.x;
    if (b > L) return;
    const float total = cdf[V - 1];
    // L is a power of two: (float)b / (float)L is exact; x*total rounding is
    // monotone in x, so lut entries bracket every key in the bucket.
    const float key = total * ((float)b / (float)L);
    int lo = 0, hi = V;
    while (lo < hi) {
        const int mid = (lo + hi) >> 1;
        if (cdf[mid] <= key) lo = mid + 1; else hi = mid;
    }
    const int ci = (lo < V) ? lo : (V - 1);
    lut[b] = make_int2(lo, __float_as_int(cdf[ci]));
}

__device__ __forceinline__ int sample_one(float uu, float total, float fL, int L, int V,
                                          const float* __restrict__ cdf,
                                          const int2* __restrict__ lut) {
    const float key = uu * total;
    int ans;
    if (L > 0) {
        int b = (int)(uu * fL);            // exact floor: fL is a power of two
        b = (b < 0) ? 0 : ((b > L - 1) ? (L - 1) : b);
        const int2 e0 = lut[b];
        const int2 e1 = lut[b + 1];
        int lo = e0.x;
        int hi = e1.x;
        if (hi <= lo) {
            ans = lo;
        } else if (hi == lo + 1) {
            // single candidate boundary; cdf[lo] is packed in the LUT entry
            ans = (__int_as_float(e0.y) <= key) ? (lo + 1) : lo;
        } else {
            while (lo < hi) {
                const int mid = (lo + hi) >> 1;
                if (cdf[mid] <= key) lo = mid + 1; else hi = mid;
            }
            ans = lo;
        }
    } else {
        int lo = 0, hi = V;
        while (lo < hi) {
            const int mid = (lo + hi) >> 1;
            if (cdf[mid] <= key) lo = mid + 1; else hi = mid;
        }
        ans = lo;
    }
    return (ans < V - 1) ? ans : (V - 1);  // clip like the reference
}

__global__ __launch_bounds__(256) void sample_kernel(const float* __restrict__ u,
                                                     const float* __restrict__ cdf,
                                                     const int2* __restrict__ lut,
                                                     float* __restrict__ out,
                                                     int N, int V, int L) {
    const int i0 = (blockIdx.x * blockDim.x + threadIdx.x) * 4;
    if (i0 >= N) return;
    const float total = cdf[V - 1];
    const float fL = (float)L;

    if (i0 + 4 <= N) {
        const float4 uv = *reinterpret_cast<const float4*>(u + i0);
        float4 ov;
        ov.x = (float)sample_one(uv.x, total, fL, L, V, cdf, lut);
        ov.y = (float)sample_one(uv.y, total, fL, L, V, cdf, lut);
        ov.z = (float)sample_one(uv.z, total, fL, L, V, cdf, lut);
        ov.w = (float)sample_one(uv.w, total, fL, L, V, cdf, lut);
        *reinterpret_cast<float4*>(out + i0) = ov;
    } else {
        for (int i = i0; i < N; ++i)
            out[i] = (float)sample_one(u[i], total, fL, L, V, cdf, lut);
    }
}

extern "C" void kernel_launch(void* const* d_in, const int* in_sizes, int n_in,
                              void* d_out, int out_size, void* d_ws, size_t ws_size,
                              hipStream_t stream) {
    const float* freq = (const float*)d_in[0];
    const float* u    = (const float*)d_in[1];
    float* out        = (float*)d_out;
    const int V = in_sizes[0];
    const int N = in_sizes[1];

    char* ws = (char*)d_ws;
    float* cdf = (float*)ws;
    const size_t cdf_bytes = (((size_t)V * 4) + 255) & ~(size_t)255;

    // Largest power-of-two LUT that fits the workspace (deterministic in ws_size).
    int L = 1 << 17;
    while (L > 1024 && cdf_bytes + ((size_t)L + 1) * 8 > ws_size) L >>= 1;
    if (cdf_bytes + ((size_t)L + 1) * 8 > ws_size) L = 0;   // fallback: plain bsearch
    int2* lut = (int2*)(ws + cdf_bytes);

    hipLaunchKernelGGL(scan_kernel, dim3(1), dim3(SCAN_T), 0, stream, freq, cdf, V);

    if (L > 0) {
        const int nthr = L + 1;
        hipLaunchKernelGGL(lut_kernel, dim3((nthr + 255) / 256), dim3(256), 0, stream,
                           cdf, V, lut, L);
    }

    const int n4 = (N + 3) / 4;
    hipLaunchKernelGGL(sample_kernel, dim3((n4 + 255) / 256), dim3(256), 0, stream,
                       u, cdf, lut, out, N, V, L);
}

// Round 5
// 28.152 us; speedup vs baseline: 1.5329x; 1.5329x over previous
//
#include <hip/hip_runtime.h>

// ---------------------------------------------------------------------------
// WeightedRandomSampler (inverse-CDF multinomial):
//   cdf = cumsum(freq); idx = searchsorted(cdf, u*total, 'right'); clip; float
//
// 4-kernel plan (scan parallelized across blocks this round):
//   1) partial_kernel   : PB blocks x 256 thr, blocksums[b] = sum of 1024-chunk
//   2) scan_write_kernel: PB blocks; block base = wave-reduced prefix of
//                         blocksums[<b]; intra-block scan (shfl_up + LDS);
//                         writes cdf as float4.
//   3) lut_kernel       : lut[b] = {searchR(total*b/L), cdf[idx]} packed 8B.
//                         L = power of two -> (float)b/L exact -> bracketing
//                         guarantee, no fudge windows.
//   4) sample_kernel    : 8 samples/thread; bucket = floor(u*L) (exact);
//                         answer in [lut[b].x, lut[b+1].x]; width 0/1 resolved
//                         from packed cdf value (no cdf load); rare wide
//                         buckets fall back to bounded binary search.
// ---------------------------------------------------------------------------

#define EPB 1024   // elements per block in the scan (256 thr x float4)

__global__ __launch_bounds__(256) void partial_kernel(const float* __restrict__ freq,
                                                      int V,
                                                      float* __restrict__ blocksums) {
    __shared__ float red[256];
    const int t = threadIdx.x;
    const int base = blockIdx.x * EPB + t * 4;
    float s = 0.f;
    if (base + 3 < V) {
        const float4 v = *reinterpret_cast<const float4*>(freq + base);
        s = v.x + v.y + v.z + v.w;
    } else {
        for (int j = 0; j < 4; ++j)
            if (base + j < V) s += freq[base + j];
    }
    red[t] = s;
    __syncthreads();
    for (int off = 128; off > 0; off >>= 1) {
        if (t < off) red[t] += red[t + off];
        __syncthreads();
    }
    if (t == 0) blocksums[blockIdx.x] = red[0];
}

__global__ __launch_bounds__(256) void scan_write_kernel(const float* __restrict__ freq,
                                                         int V,
                                                         const float* __restrict__ blocksums,
                                                         float* __restrict__ cdf) {
    __shared__ float sbase;
    __shared__ float wsum[4];
    const int t = threadIdx.x;
    const int lane = t & 63;
    const int w = t >> 6;

    // block base = sum of blocksums[0 .. blockIdx.x) — wave 0 only
    if (w == 0) {
        float v = 0.f;
        for (int i = lane; i < blockIdx.x; i += 64) v += blocksums[i];
        for (int off = 1; off <= 32; off <<= 1) v += __shfl_xor(v, off);
        if (lane == 0) sbase = v;
    }
    __syncthreads();

    // per-thread 4-element serial prefix
    const int base = blockIdx.x * EPB + t * 4;
    float v0 = 0.f, v1 = 0.f, v2 = 0.f, v3 = 0.f;
    if (base + 3 < V) {
        const float4 v = *reinterpret_cast<const float4*>(freq + base);
        v0 = v.x; v1 = v.y; v2 = v.z; v3 = v.w;
    } else {
        if (base + 0 < V) v0 = freq[base + 0];
        if (base + 1 < V) v1 = freq[base + 1];
        if (base + 2 < V) v2 = freq[base + 2];
        if (base + 3 < V) v3 = freq[base + 3];
    }
    const float p0 = v0, p1 = p0 + v1, p2 = p1 + v2, p3 = p2 + v3;
    const float s = p3;

    // inclusive wave scan of thread totals
    float sc = s;
    for (int off = 1; off <= 32; off <<= 1) {
        const float tv = __shfl_up(sc, off);
        if (lane >= off) sc += tv;
    }
    if (lane == 63) wsum[w] = sc;
    __syncthreads();
    float eb = sbase + sc - s;            // exclusive base for this thread
    for (int k = 0; k < w; ++k) eb += wsum[k];

    if (base + 3 < V) {
        float4 o;
        o.x = eb + p0; o.y = eb + p1; o.z = eb + p2; o.w = eb + p3;
        *reinterpret_cast<float4*>(cdf + base) = o;
    } else {
        if (base + 0 < V) cdf[base + 0] = eb + p0;
        if (base + 1 < V) cdf[base + 1] = eb + p1;
        if (base + 2 < V) cdf[base + 2] = eb + p2;
        if (base + 3 < V) cdf[base + 3] = eb + p3;
    }
}

__global__ __launch_bounds__(256) void lut_kernel(const float* __restrict__ cdf, int V,
                                                  int2* __restrict__ lut, int L) {
    const int b = blockIdx.x * blockDim.x + threadIdx.x;
    if (b > L) return;
    const float total = cdf[V - 1];
    // L power of two: (float)b / (float)L exact; x*total rounding monotone in x
    const float key = total * ((float)b / (float)L);
    int lo = 0, hi = V;
    while (lo < hi) {
        const int mid = (lo + hi) >> 1;
        if (cdf[mid] <= key) lo = mid + 1; else hi = mid;
    }
    const int ci = (lo < V) ? lo : (V - 1);
    lut[b] = make_int2(lo, __float_as_int(cdf[ci]));
}

__device__ __forceinline__ int sample_one(float uu, float total, float fL, int L, int V,
                                          const float* __restrict__ cdf,
                                          const int2* __restrict__ lut) {
    const float key = uu * total;
    int ans;
    if (L > 0) {
        int b = (int)(uu * fL);            // exact floor: fL is a power of two
        b = (b < 0) ? 0 : ((b > L - 1) ? (L - 1) : b);
        const int2 e0 = lut[b];
        const int2 e1 = lut[b + 1];
        int lo = e0.x;
        int hi = e1.x;
        if (hi <= lo) {
            ans = lo;
        } else if (hi == lo + 1) {
            ans = (__int_as_float(e0.y) <= key) ? (lo + 1) : lo;
        } else {
            while (lo < hi) {
                const int mid = (lo + hi) >> 1;
                if (cdf[mid] <= key) lo = mid + 1; else hi = mid;
            }
            ans = lo;
        }
    } else {
        int lo = 0, hi = V;
        while (lo < hi) {
            const int mid = (lo + hi) >> 1;
            if (cdf[mid] <= key) lo = mid + 1; else hi = mid;
        }
        ans = lo;
    }
    return (ans < V - 1) ? ans : (V - 1);  // clip like the reference
}

__global__ __launch_bounds__(256) void sample_kernel(const float* __restrict__ u,
                                                     const float* __restrict__ cdf,
                                                     const int2* __restrict__ lut,
                                                     float* __restrict__ out,
                                                     int N, int V, int L) {
    const int i0 = (blockIdx.x * blockDim.x + threadIdx.x) * 8;
    if (i0 >= N) return;
    const float total = cdf[V - 1];
    const float fL = (float)L;

    if (i0 + 8 <= N) {
        const float4 ua = *reinterpret_cast<const float4*>(u + i0);
        const float4 ub = *reinterpret_cast<const float4*>(u + i0 + 4);
        float4 oa, ob;
        oa.x = (float)sample_one(ua.x, total, fL, L, V, cdf, lut);
        oa.y = (float)sample_one(ua.y, total, fL, L, V, cdf, lut);
        oa.z = (float)sample_one(ua.z, total, fL, L, V, cdf, lut);
        oa.w = (float)sample_one(ua.w, total, fL, L, V, cdf, lut);
        ob.x = (float)sample_one(ub.x, total, fL, L, V, cdf, lut);
        ob.y = (float)sample_one(ub.y, total, fL, L, V, cdf, lut);
        ob.z = (float)sample_one(ub.z, total, fL, L, V, cdf, lut);
        ob.w = (float)sample_one(ub.w, total, fL, L, V, cdf, lut);
        *reinterpret_cast<float4*>(out + i0) = oa;
        *reinterpret_cast<float4*>(out + i0 + 4) = ob;
    } else {
        for (int i = i0; i < N; ++i)
            out[i] = (float)sample_one(u[i], total, fL, L, V, cdf, lut);
    }
}

extern "C" void kernel_launch(void* const* d_in, const int* in_sizes, int n_in,
                              void* d_out, int out_size, void* d_ws, size_t ws_size,
                              hipStream_t stream) {
    const float* freq = (const float*)d_in[0];
    const float* u    = (const float*)d_in[1];
    float* out        = (float*)d_out;
    const int V = in_sizes[0];
    const int N = in_sizes[1];
    const int PB = (V + EPB - 1) / EPB;   // scan blocks (50 for V=50257)

    char* ws = (char*)d_ws;
    float* cdf = (float*)ws;
    const size_t cdf_bytes = (((size_t)V * 4) + 255) & ~(size_t)255;
    const size_t bs_bytes  = (((size_t)PB * 4) + 255) & ~(size_t)255;

    // Largest power-of-two LUT that fits the workspace (deterministic in ws_size).
    int L = 1 << 17;
    while (L > 1024 && cdf_bytes + bs_bytes + ((size_t)L + 1) * 8 > ws_size) L >>= 1;
    if (cdf_bytes + bs_bytes + ((size_t)L + 1) * 8 > ws_size) L = 0;
    float* blocksums = (float*)(ws + cdf_bytes);
    int2* lut = (int2*)(ws + cdf_bytes + bs_bytes);

    hipLaunchKernelGGL(partial_kernel, dim3(PB), dim3(256), 0, stream,
                       freq, V, blocksums);
    hipLaunchKernelGGL(scan_write_kernel, dim3(PB), dim3(256), 0, stream,
                       freq, V, blocksums, cdf);

    if (L > 0) {
        const int nthr = L + 1;
        hipLaunchKernelGGL(lut_kernel, dim3((nthr + 255) / 256), dim3(256), 0, stream,
                           cdf, V, lut, L);
    }

    const int n8 = (N + 7) / 8;
    hipLaunchKernelGGL(sample_kernel, dim3((n8 + 255) / 256), dim3(256), 0, stream,
                       u, cdf, lut, out, N, V, L);
}

// Round 6
// 19.325 us; speedup vs baseline: 2.2330x; 1.4567x over previous
//
#include <hip/hip_runtime.h>
#include <math.h>

// ---------------------------------------------------------------------------
// WeightedRandomSampler (inverse-CDF multinomial), SINGLE-KERNEL design:
//   Each block independently (redundantly) builds a group-level CDF in LDS:
//     group g = freq[16g .. 16g+16); cdfS[g] = cdf[16g+15]  (G = ceil(V/16))
//   stored in a bank-de-conflicted padded layout phys(i) = i + i/32
//   (binary search strides are powers of two -> without padding every probe
//    of stride>=32 floats hits the same bank = 32-way conflict).
//   Per sample: key = u*total; 12-level branchless LDS bsearch -> group g;
//   reload that group's 16 freqs (one 64B L2-hot line), sequential prefix +
//   compare-count -> exact searchsorted(cdf, key, 'right'); clip; float out.
//   Redundant scan = 256 blocks x 200KB = 50MB of L2-resident broadcast
//   (~1.5us) -- cheaper than extra kernel launches + inter-dispatch gaps.
//   No workspace, no atomics, no inter-block ordering assumptions.
// ---------------------------------------------------------------------------

#define TPB 512       // threads per block (8 waves)
#define SPT 8         // samples per thread
#define GRP 16        // freq elements per group
#define GPT_MAX 16    // max groups per thread (supports V <= 131072)

__device__ __forceinline__ int physIdx(int i) { return i + (i >> 5); }

template <int PAD>
__global__ __launch_bounds__(TPB) void sampler_kernel(const float* __restrict__ freq,
                                                      const float* __restrict__ u,
                                                      float* __restrict__ out,
                                                      int N, int V, int G) {
    __shared__ float sS[PAD + (PAD >> 5)];   // padded group-CDF
    __shared__ float wsum[TPB / 64];
    const int t = threadIdx.x;
    const int lane = t & 63;
    const int w = t >> 6;

    // ---- phase 1: per-block redundant group-sum scan ----
    const int GPT = (G + TPB - 1) / TPB;     // 7 for V=50257
    const int g0 = t * GPT;

    float ls[GPT_MAX];                       // compile-time indexed (unrolled)
    float runv = 0.f;
#pragma unroll
    for (int k = 0; k < GPT_MAX; ++k) {
        float s = 0.f;
        if (k < GPT) {
            const int g = g0 + k;
            if (g < G) {
                const int base = g * GRP;
                if (base + GRP <= V) {
                    const float4* fp = reinterpret_cast<const float4*>(freq + base);
                    const float4 a = fp[0], b = fp[1], c = fp[2], d = fp[3];
                    s = a.x; s += a.y; s += a.z; s += a.w;
                    s += b.x; s += b.y; s += b.z; s += b.w;
                    s += c.x; s += c.y; s += c.z; s += c.w;
                    s += d.x; s += d.y; s += d.z; s += d.w;
                } else {                      // tail group, guarded
                    for (int j = 0; j < GRP; ++j) {
                        const int idx = base + j;
                        if (idx < V) s += freq[idx];
                    }
                }
            }
        }
        runv += s;
        ls[k] = runv;                        // local inclusive scan
    }

    // wave-inclusive scan of thread totals, then cross-wave bases
    float sc = runv;
#pragma unroll
    for (int off = 1; off <= 32; off <<= 1) {
        const float v = __shfl_up(sc, off);
        if (lane >= off) sc += v;
    }
    if (lane == 63) wsum[w] = sc;
    __syncthreads();
    float tbase = sc - runv;                 // exclusive base for this thread
    for (int k = 0; k < w; ++k) tbase += wsum[k];

#pragma unroll
    for (int k = 0; k < GPT_MAX; ++k) {
        if (k < GPT) {
            const int g = g0 + k;
            if (g < G) sS[physIdx(g)] = tbase + ls[k];
        }
    }
    for (int i = G + t; i < PAD; i += TPB) sS[physIdx(i)] = INFINITY;  // pads
    __syncthreads();

    const float total = sS[physIdx(G - 1)];  // broadcast LDS read

    // ---- phase 2: sample ----
    const int gid = blockIdx.x * TPB + t;
    const long long i0 = (long long)gid * SPT;
    if (i0 >= N) return;                     // after all barriers

    float uk[SPT];
    if (i0 + SPT <= N) {
        const float4 A = *reinterpret_cast<const float4*>(u + i0);
        const float4 B = *reinterpret_cast<const float4*>(u + i0 + 4);
        uk[0] = A.x; uk[1] = A.y; uk[2] = A.z; uk[3] = A.w;
        uk[4] = B.x; uk[5] = B.y; uk[6] = B.z; uk[7] = B.w;
    } else {
#pragma unroll
        for (int s = 0; s < SPT; ++s) uk[s] = (i0 + s < N) ? u[i0 + s] : 0.f;
    }

    float ok[SPT];
#pragma unroll
    for (int s = 0; s < SPT; ++s) {
        const float key = uk[s] * total;

        // branchless "count of entries <= key" over PAD sorted values
        int pos = -1;
#pragma unroll
        for (int step = PAD >> 1; step >= 1; step >>= 1) {
            const int j = pos + step;        // always in [0, PAD-2]
            pos += (sS[physIdx(j)] <= key) ? step : 0;
        }
        int g = pos + 1;                     // group holding the boundary
        g = (g > G - 1) ? (G - 1) : g;
        const float base = (g > 0) ? sS[physIdx(g - 1)] : 0.f;
        const int eb = g * GRP;

        float r = base;
        int cnt = 0;
        if (eb + GRP <= V) {
            const float4* fp = reinterpret_cast<const float4*>(freq + eb);
            const float4 a = fp[0], b = fp[1], c = fp[2], d = fp[3];
            r += a.x; cnt += (r <= key); r += a.y; cnt += (r <= key);
            r += a.z; cnt += (r <= key); r += a.w; cnt += (r <= key);
            r += b.x; cnt += (r <= key); r += b.y; cnt += (r <= key);
            r += b.z; cnt += (r <= key); r += b.w; cnt += (r <= key);
            r += c.x; cnt += (r <= key); r += c.y; cnt += (r <= key);
            r += c.z; cnt += (r <= key); r += c.w; cnt += (r <= key);
            r += d.x; cnt += (r <= key); r += d.y; cnt += (r <= key);
            r += d.z; cnt += (r <= key); r += d.w; cnt += (r <= key);
        } else {                             // tail group, guarded
            for (int j = 0; j < GRP; ++j) {
                const int idx = eb + j;
                if (idx < V) { r += freq[idx]; cnt += (r <= key); }
            }
        }
        int ans = eb + cnt;                  // searchsorted 'right'
        ans = (ans > V - 1) ? (V - 1) : ans; // clip like reference
        ok[s] = (float)ans;
    }

    if (i0 + SPT <= N) {
        *reinterpret_cast<float4*>(out + i0)     = make_float4(ok[0], ok[1], ok[2], ok[3]);
        *reinterpret_cast<float4*>(out + i0 + 4) = make_float4(ok[4], ok[5], ok[6], ok[7]);
    } else {
        for (int s = 0; s < SPT; ++s)
            if (i0 + s < N) out[i0 + s] = ok[s];
    }
}

extern "C" void kernel_launch(void* const* d_in, const int* in_sizes, int n_in,
                              void* d_out, int out_size, void* d_ws, size_t ws_size,
                              hipStream_t stream) {
    const float* freq = (const float*)d_in[0];
    const float* u    = (const float*)d_in[1];
    float* out        = (float*)d_out;
    const int V = in_sizes[0];
    const int N = in_sizes[1];
    const int G = (V + GRP - 1) / GRP;                 // 3142 for V=50257
    const int NB = (N + TPB * SPT - 1) / (TPB * SPT);  // 256 for N=2^20

    // PAD = smallest pow2 > G (need at least one +INF pad entry)
    if (G < 1024) {
        hipLaunchKernelGGL(sampler_kernel<1024>, dim3(NB), dim3(TPB), 0, stream,
                           freq, u, out, N, V, G);
    } else if (G < 2048) {
        hipLaunchKernelGGL(sampler_kernel<2048>, dim3(NB), dim3(TPB), 0, stream,
                           freq, u, out, N, V, G);
    } else if (G < 4096) {
        hipLaunchKernelGGL(sampler_kernel<4096>, dim3(NB), dim3(TPB), 0, stream,
                           freq, u, out, N, V, G);
    } else {
        hipLaunchKernelGGL(sampler_kernel<8192>, dim3(NB), dim3(TPB), 0, stream,
                           freq, u, out, N, V, G);
    }
}